// Round 16
// baseline (266.214 us; speedup 1.0000x reference)
//
#include <hip/hip_runtime.h>

#define F 64
#define H 64
#define NT 256
#define TILE_ROWS 256     // 4 waves x 64 wave-private rows (4 independent 16-row chains)
#define ITERS 4
#define ROWS_PER_BLOCK (TILE_ROWS * ITERS)   // 1024
#define WPAD 72           // LDS row stride in bf16 elems (144 B)

typedef __bf16 bf16;
typedef __attribute__((ext_vector_type(8))) __bf16 bf16x8;
typedef __attribute__((ext_vector_type(4))) float f32x4;

__device__ __forceinline__ float celu1(float v) {
    // CELU(alpha=1): x>0 ? x : exp(x)-1
    float e = __expf(v) - 1.0f;
    return v > 0.0f ? v : e;
}

// R15 zero-LDS-roundtrip structure widened to 4 independent n-chains per wave (R11's
// validated ILP lever). Per block: one feature f x 1024 rows; 4 waves x 64 rows/tile.
//  - layer-in (rank-1): per-lane fp32 FMA directly into hidden-0 B-fragments.
//  - hidden-0 -> hidden-1: MFMA k-permutation invariance. k' = 16*(j>>1)+4q+2kk+(j&1);
//    wlds[1] stores W1 in that k-order, so D0 is B1 after an in-lane register repack
//    fused into the m-loop (acc released per m -- R14's spill fix). Validated R14/R15.
//  - hidden-1 + output dot in registers (w_out indexed out=16m+4q+rr = D rows),
//    quad shfl-reduce, store.
// (NT,3): cap 170. min-waves=4 (cap 128) spilled in ALL FOUR attempts (R4/R5/R9/R13)
// -- do not retry. Spill signature: reported VGPR==64 / FETCH>300MB scratch traffic.
// Est. live set ~152 regs.
__global__ __launch_bounds__(NT, 3) void mlp64(
    const float* __restrict__ x,      // [B,F]
    const float* __restrict__ w_in,
    const float* __restrict__ b_in,
    const float* __restrict__ w_hid,
    const float* __restrict__ b_hid,
    const float* __restrict__ w_out,
    const float* __restrict__ b_out,
    float* __restrict__ out,          // [B,F]
    int Btot)
{
    const int f    = blockIdx.x & (F - 1);
    const int blk  = blockIdx.x >> 6;
    const int row0 = blk * ROWS_PER_BLOCK;
    const int t    = threadIdx.x;
    const int lane = t & 63;
    const int l15  = lane & 15;
    const int q    = lane >> 4;
    const int wrow = (t >> 6) * 64;   // wave-private 64-row slice

    __shared__ __align__(16) bf16 wlds[2][H][WPAD];   // [0]=hidden0 natural, [1]=hidden1 k-permuted
    __shared__ __align__(16) float s_bias[2][H];      // hidden biases

    // ---- stage weights (fp32 -> bf16); wlds[1] gets the k-permuted layout ----
    for (int idx = t; idx < 1024; idx += NT) {
        const int l = idx >> 9, rc = idx & 511, row = rc >> 3, c = rc & 7;
        if (l == 0) {
            const float* p = w_hid + ((size_t)f << 12) + (row << 6) + (c << 3);
            float4 a = *(const float4*)p, b = *(const float4*)(p + 4);
            bf16x8 v;
            v[0] = (bf16)a.x; v[1] = (bf16)a.y; v[2] = (bf16)a.z; v[3] = (bf16)a.w;
            v[4] = (bf16)b.x; v[5] = (bf16)b.y; v[6] = (bf16)b.z; v[7] = (bf16)b.w;
            *(bf16x8*)&wlds[0][row][c * 8] = v;
        } else {
            // c = qq*2 + kk; dst chunk [qq*16 + kk*8 + j] <- W1[row][16*(j>>1) + 4qq + 2kk + (j&1)]
            const int qq = c >> 1, kk = c & 1, base = 4 * qq + 2 * kk;
            const float* p = w_hid + (((size_t)F + f) << 12) + (row << 6) + base;
            bf16x8 v;
            #pragma unroll
            for (int mp = 0; mp < 4; ++mp) {
                float2 pr = *(const float2*)(p + 16 * mp);
                v[2 * mp]     = (bf16)pr.x;
                v[2 * mp + 1] = (bf16)pr.y;
            }
            *(bf16x8*)&wlds[1][row][qq * 16 + kk * 8] = v;
        }
    }
    if (t < H)          s_bias[0][t]     = b_hid[f * H + t];
    else if (t < 2 * H) s_bias[1][t - H] = b_hid[F * H + f * H + (t - H)];
    __syncthreads();

    // ---- per-lane layer-in weights/biases: in-index = 32kk + 8q + j ----
    float w16[16], b16[16];
    {
        const float* wp = w_in + f * H + q * 8;
        const float* bp = b_in + f * H + q * 8;
        #pragma unroll
        for (int kk = 0; kk < 2; ++kk) {
            float4 a = *(const float4*)(wp + kk * 32), b = *(const float4*)(wp + kk * 32 + 4);
            float4 c = *(const float4*)(bp + kk * 32), d = *(const float4*)(bp + kk * 32 + 4);
            w16[kk*8+0]=a.x; w16[kk*8+1]=a.y; w16[kk*8+2]=a.z; w16[kk*8+3]=a.w;
            w16[kk*8+4]=b.x; w16[kk*8+5]=b.y; w16[kk*8+6]=b.z; w16[kk*8+7]=b.w;
            b16[kk*8+0]=c.x; b16[kk*8+1]=c.y; b16[kk*8+2]=c.z; b16[kk*8+3]=c.w;
            b16[kk*8+4]=d.x; b16[kk*8+5]=d.y; b16[kk*8+6]=d.z; b16[kk*8+7]=d.w;
        }
    }

    f32x4 wo4[4];
    #pragma unroll
    for (int m = 0; m < 4; ++m)
        wo4[m] = *(const f32x4*)(w_out + f * H + m * 16 + q * 4);
    const float bo = b_out[f];

    float xc[4], xn[4];
    #pragma unroll
    for (int n = 0; n < 4; ++n)
        xc[n] = x[(size_t)(row0 + wrow + n * 16 + l15) * F + f];

    #pragma unroll 1
    for (int it = 0; it < ITERS; ++it) {
        const int rbase = row0 + it * TILE_ROWS + wrow;

        #pragma unroll
        for (int n = 0; n < 4; ++n)
            xn[n] = (it + 1 < ITERS)
                  ? x[(size_t)(rbase + TILE_ROWS + n * 16 + l15) * F + f] : 0.0f;

        // ---- layer in->H: rank-1 -> hidden-0 B-fragments (exact fp32) ----
        bf16x8 Bh[4][2];   // [n][kk]: B[k=32kk+8q+j][batch=n*16+l15]
        #pragma unroll
        for (int n = 0; n < 4; ++n) {
            const float xv = xc[n];
            #pragma unroll
            for (int kk = 0; kk < 2; ++kk) {
                bf16x8 v;
                #pragma unroll
                for (int j = 0; j < 8; ++j)
                    v[j] = (bf16)celu1(fmaf(xv, w16[kk * 8 + j], b16[kk * 8 + j]));
                Bh[n][kk] = v;
            }
        }

        // ---- hidden layer 0 fused with k-permutation repack (acc released per m) ----
        bf16x8 Bg[4][2];   // hidden-1 B frags, filled 2 slots per (m,kk)
        #pragma unroll
        for (int m = 0; m < 4; ++m) {
            bf16x8 A0 = *(const bf16x8*)&wlds[0][m * 16 + l15][q * 8];
            bf16x8 A1 = *(const bf16x8*)&wlds[0][m * 16 + l15][32 + q * 8];
            f32x4 c0  = *(const f32x4*)&s_bias[0][m * 16 + q * 4];
            #pragma unroll
            for (int n = 0; n < 4; ++n) {
                f32x4 a = __builtin_amdgcn_mfma_f32_16x16x32_bf16(A0, Bh[n][0], c0, 0, 0, 0);
                a       = __builtin_amdgcn_mfma_f32_16x16x32_bf16(A1, Bh[n][1], a, 0, 0, 0);
                Bg[n][0][2 * m]     = (bf16)celu1(a[0]);
                Bg[n][0][2 * m + 1] = (bf16)celu1(a[1]);
                Bg[n][1][2 * m]     = (bf16)celu1(a[2]);
                Bg[n][1][2 * m + 1] = (bf16)celu1(a[3]);
            }
        }

        // ---- hidden layer 1 (permuted weights) + output dot in registers ----
        {
            float s[4] = {0.0f, 0.0f, 0.0f, 0.0f};
            #pragma unroll
            for (int m = 0; m < 4; ++m) {
                bf16x8 A0 = *(const bf16x8*)&wlds[1][m * 16 + l15][q * 16];
                bf16x8 A1 = *(const bf16x8*)&wlds[1][m * 16 + l15][q * 16 + 8];
                f32x4 c0  = *(const f32x4*)&s_bias[1][m * 16 + q * 4];
                #pragma unroll
                for (int n = 0; n < 4; ++n) {
                    f32x4 a = __builtin_amdgcn_mfma_f32_16x16x32_bf16(A0, Bg[n][0], c0, 0, 0, 0);
                    a       = __builtin_amdgcn_mfma_f32_16x16x32_bf16(A1, Bg[n][1], a, 0, 0, 0);
                    #pragma unroll
                    for (int rr = 0; rr < 4; ++rr)
                        s[n] = fmaf(celu1(a[rr]), wo4[m][rr], s[n]);
                }
            }
            #pragma unroll
            for (int n = 0; n < 4; ++n) {
                s[n] += __shfl_xor(s[n], 16, 64);
                s[n] += __shfl_xor(s[n], 32, 64);
            }
            if (q == 0) {
                #pragma unroll
                for (int n = 0; n < 4; ++n)
                    out[(size_t)(rbase + n * 16 + l15) * F + f] = s[n] + bo;
            }
        }

        #pragma unroll
        for (int n = 0; n < 4; ++n) xc[n] = xn[n];
    }
}

extern "C" void kernel_launch(void* const* d_in, const int* in_sizes, int n_in,
                              void* d_out, int out_size, void* d_ws, size_t ws_size,
                              hipStream_t stream) {
    const float* x     = (const float*)d_in[0];
    const float* w_in  = (const float*)d_in[1];
    const float* b_in  = (const float*)d_in[2];
    const float* w_hid = (const float*)d_in[3];
    const float* b_hid = (const float*)d_in[4];
    const float* w_out = (const float*)d_in[5];
    const float* b_out = (const float*)d_in[6];
    float* out = (float*)d_out;

    const int Btot = in_sizes[0] / F;                       // 32768
    dim3 grid((unsigned)((Btot / ROWS_PER_BLOCK) * F));     // 2048 blocks
    dim3 block(NT);
    mlp64<<<grid, block, 0, stream>>>(x, w_in, b_in, w_hid, b_hid, w_out, b_out, out, Btot);
}